// Round 1
// baseline (3911.097 us; speedup 1.0000x reference)
//
#include <hip/hip_runtime.h>
#include <cstdint>
#include <cstddef>

#define EPSV 1e-5f

constexpr int Bn = 64;
constexpr int Tt = 2000;
constexpr int Hh = 192;
constexpr int TILE_T = 128;
constexpr int CI = 12;   // channel chunk (divides 264 and 192)

// MODE: 0 = TCN1 (conv residual), 1 = TCN2 (identity residual), 2 = TCN3 (identity residual + snn-BN fold)
template<int K, int D, int CIN, int MODE>
__global__ __launch_bounds__(256, 2) void conv_tcn(
    const float* __restrict__ xin,   // [B, CIN, T]
    const float* __restrict__ wg,    // [64, CIN, K]  (this o-group's weights)
    const float* __restrict__ bias,  // [64]
    const float* __restrict__ gg, const float* __restrict__ gb,
    const float* __restrict__ gm, const float* __restrict__ gv,   // BN over [192]
    const float* __restrict__ rw, const float* __restrict__ rb,   // [192,CIN],[192] (MODE 0)
    const float* __restrict__ sg, const float* __restrict__ sb,
    const float* __restrict__ sm, const float* __restrict__ sv,   // snn BN (MODE 2)
    float* __restrict__ outp,        // [B, 192, T]
    int o0)
{
    constexpr int PAD   = (K - 1) / 2 * D;
    constexpr int XSTR  = (TILE_T + 2 * PAD + 3) / 4 * 4;
    constexpr int SPANQ = (8 + (K - 1) * D + 3) / 4;
    constexpr int WP    = (K <= 3) ? 4 : 8;
    constexpr int WROW  = ((63 * WP + (63 >> 2) * 4 + WP + 3) / 4) * 4;
    static_assert(CIN % CI == 0, "CI must divide CIN");

    __shared__ float xs[CI * XSTR];
    __shared__ float ws[CI * WROW];
    __shared__ float rws[(MODE == 0) ? (CI * 64) : 4];

    const int tid = threadIdx.x;
    const int tx  = tid & 15;   // t quadrant: 8 consecutive t each
    const int ty  = tid >> 4;   // o quadrant: 4 consecutive o each
    const int b   = blockIdx.y;
    const int t0  = blockIdx.x * TILE_T;

    float acc[4][8];
#pragma unroll
    for (int i = 0; i < 4; ++i)
#pragma unroll
        for (int j = 0; j < 8; ++j) acc[i][j] = 0.f;

    float accres[(MODE == 0) ? 4 : 1][(MODE == 0) ? 8 : 1];
    if constexpr (MODE == 0) {
#pragma unroll
        for (int i = 0; i < 4; ++i)
#pragma unroll
            for (int j = 0; j < 8; ++j) accres[i][j] = 0.f;
    }

    for (int ci0 = 0; ci0 < CIN; ci0 += CI) {
        __syncthreads();
        // ---- stage x chunk: rows [ci0, ci0+CI), cols t0-PAD .. t0-PAD+XSTR
        for (int idx = tid; idx < CI * XSTR; idx += 256) {
            int r = idx / XSTR;
            int c = idx - r * XSTR;
            int t = t0 - PAD + c;
            float v = 0.f;
            if (t >= 0 && t < Tt) v = xin[((size_t)b * CIN + (ci0 + r)) * Tt + t];
            xs[idx] = v;
        }
        // ---- stage weights (o-swizzled to avoid 4-way LDS bank conflict)
        for (int idx = tid; idx < 64 * CI * K; idx += 256) {
            int o   = idx / (CI * K);
            int rem = idx - o * (CI * K);
            int r   = rem / K;
            int j   = rem - r * K;
            ws[r * WROW + o * WP + ((o >> 2) << 2) + j] =
                wg[(size_t)o * CIN * K + (size_t)(ci0 + r) * K + j];
        }
        if constexpr (MODE == 0) {
            for (int idx = tid; idx < CI * 64; idx += 256) {
                int r = idx >> 6, o = idx & 63;
                rws[idx] = rw[(size_t)(o0 + o) * CIN + (ci0 + r)];
            }
        }
        __syncthreads();

#pragma unroll
        for (int ci = 0; ci < CI; ++ci) {
            float xa[SPANQ * 4];
            const float4* xr = reinterpret_cast<const float4*>(&xs[ci * XSTR]) + tx * 2;
#pragma unroll
            for (int q = 0; q < SPANQ; ++q) {
                float4 v = xr[q];
                xa[4 * q + 0] = v.x; xa[4 * q + 1] = v.y;
                xa[4 * q + 2] = v.z; xa[4 * q + 3] = v.w;
            }
            float wa[4][WP];
            const float* wrow = &ws[ci * WROW];
#pragma unroll
            for (int oo = 0; oo < 4; ++oo) {
                int o = ty * 4 + oo;
                const float4* wp4 = reinterpret_cast<const float4*>(&wrow[o * WP + ((o >> 2) << 2)]);
                float4 w0 = wp4[0];
                wa[oo][0] = w0.x; wa[oo][1] = w0.y; wa[oo][2] = w0.z; wa[oo][3] = w0.w;
                if constexpr (WP == 8) {
                    float4 w1 = wp4[1];
                    wa[oo][4] = w1.x; wa[oo][5] = w1.y; wa[oo][6] = w1.z; wa[oo][7] = w1.w;
                }
            }
#pragma unroll
            for (int j = 0; j < K; ++j) {
#pragma unroll
                for (int oo = 0; oo < 4; ++oo) {
#pragma unroll
                    for (int tt = 0; tt < 8; ++tt)
                        acc[oo][tt] = fmaf(wa[oo][j], xa[j * D + tt], acc[oo][tt]);
                }
            }
            if constexpr (MODE == 0) {
                float4 rv = *reinterpret_cast<const float4*>(&rws[ci * 64 + ty * 4]);
                float rr[4] = {rv.x, rv.y, rv.z, rv.w};
#pragma unroll
                for (int oo = 0; oo < 4; ++oo)
#pragma unroll
                    for (int tt = 0; tt < 8; ++tt)
                        accres[oo][tt] = fmaf(rr[oo], xa[PAD + tt], accres[oo][tt]);
            }
        }
    }

    // ---- epilogue: BN fold + ReLU + residual (+ snn BN fold) + store
    const int tb = t0 + tx * 8;
    if (tb >= Tt) return;   // Tt % 8 == 0 => either all 8 valid or none
#pragma unroll
    for (int oo = 0; oo < 4; ++oo) {
        const int og = o0 + ty * 4 + oo;
        const float sc = gg[og] / sqrtf(gv[og] + EPSV);
        const float be = (bias[ty * 4 + oo] - gm[og]) * sc + gb[og];
        float vout[8];
#pragma unroll
        for (int tt = 0; tt < 8; ++tt) {
            float v = acc[oo][tt] * sc + be;
            vout[tt] = v > 0.f ? v : 0.f;
        }
        if constexpr (MODE == 0) {
            const float rbv = rb[og];
#pragma unroll
            for (int tt = 0; tt < 8; ++tt) vout[tt] += accres[oo][tt] + rbv;
        } else {
            const float4* xres = reinterpret_cast<const float4*>(&xin[((size_t)b * CIN + og) * Tt + tb]);
            float4 r0 = xres[0], r1 = xres[1];
            vout[0] += r0.x; vout[1] += r0.y; vout[2] += r0.z; vout[3] += r0.w;
            vout[4] += r1.x; vout[5] += r1.y; vout[6] += r1.z; vout[7] += r1.w;
        }
        if constexpr (MODE == 2) {
            const float s2 = sg[og] / sqrtf(sv[og] + EPSV);
            const float b2 = sb[og] - sm[og] * s2;
#pragma unroll
            for (int tt = 0; tt < 8; ++tt) vout[tt] = vout[tt] * s2 + b2;
        }
        float4* op = reinterpret_cast<float4*>(&outp[((size_t)b * Hh + og) * Tt + tb]);
        op[0] = make_float4(vout[0], vout[1], vout[2], vout[3]);
        op[1] = make_float4(vout[4], vout[5], vout[6], vout[7]);
    }
}

// ---------------- SNN + attention + classifier, one block per batch ----------------
__global__ __launch_bounds__(192) void snn_head(
    const float* __restrict__ hin,   // [B,192,T]  (snn-BN already folded)
    const float* __restrict__ plif,
    const float* __restrict__ aw, const float* __restrict__ ab,
    const float* __restrict__ c1w, const float* __restrict__ c1b,
    const float* __restrict__ c1g, const float* __restrict__ c1bb,
    const float* __restrict__ c1m, const float* __restrict__ c1v,
    const float* __restrict__ c2w, const float* __restrict__ c2b,
    const float* __restrict__ c2g, const float* __restrict__ c2bb,
    const float* __restrict__ c2m, const float* __restrict__ c2v,
    const float* __restrict__ c3w, const float* __restrict__ c3b,
    float* __restrict__ outp)        // [B,4]
{
    __shared__ uint32_t bits[192 * 65];   // spike bitmask, stride 65 words (bank-spread)
    __shared__ float scl[2048];           // scores -> softmax numerators
    __shared__ float red[8];
    __shared__ float pooled[192];
    __shared__ float z1[128];
    __shared__ float z2[64];

    const int tid = threadIdx.x;       // == h index, 0..191
    const int b   = blockIdx.x;
    const float decay = 1.f / (1.f + expf(-plif[0]));

    if (tid < 48) scl[2000 + tid] = 0.f;   // guard tail reads in phase 3

    // ---- phase 1: LIF scan over T, pack spikes into bits
    const float* row = hin + ((size_t)b * Hh + tid) * Tt;
    float v = 0.f;
    for (int c = 0; c < 62; ++c) {
        const float4* rq = reinterpret_cast<const float4*>(row + c * 32);
        float xa[32];
#pragma unroll
        for (int q = 0; q < 8; ++q) {
            float4 t4 = rq[q];
            xa[4 * q + 0] = t4.x; xa[4 * q + 1] = t4.y;
            xa[4 * q + 2] = t4.z; xa[4 * q + 3] = t4.w;
        }
        uint32_t wv = 0;
#pragma unroll
        for (int k = 0; k < 32; ++k) {
            v = fmaf(xa[k] - v, decay, v);       // v += (x - v)*decay
            if (v >= 1.f) { wv |= (1u << k); v = 0.f; }
        }
        bits[tid * 65 + c] = wv;
    }
    {   // tail: t = 1984..1999
        const float4* rq = reinterpret_cast<const float4*>(row + 62 * 32);
        float xa[16];
#pragma unroll
        for (int q = 0; q < 4; ++q) {
            float4 t4 = rq[q];
            xa[4 * q + 0] = t4.x; xa[4 * q + 1] = t4.y;
            xa[4 * q + 2] = t4.z; xa[4 * q + 3] = t4.w;
        }
        uint32_t wv = 0;
#pragma unroll
        for (int k = 0; k < 16; ++k) {
            v = fmaf(xa[k] - v, decay, v);
            if (v >= 1.f) { wv |= (1u << k); v = 0.f; }
        }
        bits[tid * 65 + 62] = wv;
    }
    __syncthreads();

    // ---- phase 2: attention scores; spikes binary => tanh(a) = s * tanh(1)
    const float tanh1 = 0.7615941559557649f;
    const float abv   = ab[0];
    for (int t = tid; t < Tt; t += 192) {
        const int wd = t >> 5, bp = t & 31;
        float s = 0.f;
#pragma unroll 8
        for (int hh = 0; hh < 192; ++hh)
            s += ((bits[hh * 65 + wd] >> bp) & 1u) ? aw[hh] : 0.f;
        scl[t] = s * tanh1 + abv;
    }
    __syncthreads();

    // ---- softmax over T
    float lm = -1e30f;
    for (int t = tid; t < Tt; t += 192) lm = fmaxf(lm, scl[t]);
#pragma unroll
    for (int off = 32; off > 0; off >>= 1) lm = fmaxf(lm, __shfl_xor(lm, off));
    if ((tid & 63) == 0) red[tid >> 6] = lm;
    __syncthreads();
    const float m = fmaxf(red[0], fmaxf(red[1], red[2]));
    float ls = 0.f;
    for (int t = tid; t < Tt; t += 192) {
        float e = expf(scl[t] - m);
        scl[t] = e;
        ls += e;
    }
#pragma unroll
    for (int off = 32; off > 0; off >>= 1) ls += __shfl_xor(ls, off);
    if ((tid & 63) == 0) red[4 + (tid >> 6)] = ls;
    __syncthreads();
    const float inv = 1.f / (red[4] + red[5] + red[6]);

    // ---- phase 3: pooled[h] = sum_t s(t,h) * softmax_w(t)
    float p = 0.f;
    for (int wd = 0; wd < 63; ++wd) {
        uint32_t bw = bits[tid * 65 + wd];
        if (bw) {
#pragma unroll
            for (int k = 0; k < 32; ++k)
                if ((bw >> k) & 1u) p += scl[wd * 32 + k];
        }
    }
    pooled[tid] = p * inv;
    __syncthreads();

    // ---- phase 4: classifier  gelu(bn(fc1)) -> gelu(bn(fc2)) -> fc3
    if (tid < 128) {
        const float4* wr = reinterpret_cast<const float4*>(c1w + (size_t)tid * 192);
        const float4* pr = reinterpret_cast<const float4*>(pooled);
        float s = 0.f;
#pragma unroll 8
        for (int q = 0; q < 48; ++q) {
            float4 wv4 = wr[q]; float4 pv4 = pr[q];
            s += wv4.x * pv4.x + wv4.y * pv4.y + wv4.z * pv4.z + wv4.w * pv4.w;
        }
        s += c1b[tid];
        s = (s - c1m[tid]) * (c1g[tid] / sqrtf(c1v[tid] + EPSV)) + c1bb[tid];
        s = s * 0.5f * (1.f + erff(s * 0.70710678118654752f));
        z1[tid] = s;
    }
    __syncthreads();
    if (tid < 64) {
        const float4* wr = reinterpret_cast<const float4*>(c2w + (size_t)tid * 128);
        const float4* zr = reinterpret_cast<const float4*>(z1);
        float s = 0.f;
#pragma unroll 8
        for (int q = 0; q < 32; ++q) {
            float4 wv4 = wr[q]; float4 zv4 = zr[q];
            s += wv4.x * zv4.x + wv4.y * zv4.y + wv4.z * zv4.z + wv4.w * zv4.w;
        }
        s += c2b[tid];
        s = (s - c2m[tid]) * (c2g[tid] / sqrtf(c2v[tid] + EPSV)) + c2bb[tid];
        s = s * 0.5f * (1.f + erff(s * 0.70710678118654752f));
        z2[tid] = s;
    }
    __syncthreads();
    if (tid < 4) {
        float s = c3b[tid];
#pragma unroll 8
        for (int hh = 0; hh < 64; ++hh) s += z2[hh] * c3w[tid * 64 + hh];
        outp[b * 4 + tid] = s;
    }
}

extern "C" void kernel_launch(void* const* d_in, const int* in_sizes, int n_in,
                              void* d_out, int out_size, void* d_ws, size_t ws_size,
                              hipStream_t stream) {
    (void)in_sizes; (void)n_in; (void)out_size; (void)ws_size;
    // setup_inputs() dict order:
    const float* x     = (const float*)d_in[0];
    const float* t1_w3 = (const float*)d_in[1];
    const float* t1_b3 = (const float*)d_in[2];
    const float* t1_w5 = (const float*)d_in[3];
    const float* t1_b5 = (const float*)d_in[4];
    const float* t1_w7 = (const float*)d_in[5];
    const float* t1_b7 = (const float*)d_in[6];
    const float* t1_g  = (const float*)d_in[7];
    const float* t1_bb = (const float*)d_in[8];
    const float* t1_m  = (const float*)d_in[9];
    const float* t1_v  = (const float*)d_in[10];
    const float* t2_w3 = (const float*)d_in[11];
    const float* t2_b3 = (const float*)d_in[12];
    const float* t2_w5 = (const float*)d_in[13];
    const float* t2_b5 = (const float*)d_in[14];
    const float* t2_w7 = (const float*)d_in[15];
    const float* t2_b7 = (const float*)d_in[16];
    const float* t2_g  = (const float*)d_in[17];
    const float* t2_bb = (const float*)d_in[18];
    const float* t2_m  = (const float*)d_in[19];
    const float* t2_v  = (const float*)d_in[20];
    const float* t3_w3 = (const float*)d_in[21];
    const float* t3_b3 = (const float*)d_in[22];
    const float* t3_w5 = (const float*)d_in[23];
    const float* t3_b5 = (const float*)d_in[24];
    const float* t3_w7 = (const float*)d_in[25];
    const float* t3_b7 = (const float*)d_in[26];
    const float* t3_g  = (const float*)d_in[27];
    const float* t3_bb = (const float*)d_in[28];
    const float* t3_m  = (const float*)d_in[29];
    const float* t3_v  = (const float*)d_in[30];
    const float* t1_rw = (const float*)d_in[31];
    const float* t1_rb = (const float*)d_in[32];
    const float* snn_g = (const float*)d_in[33];
    const float* snn_bb= (const float*)d_in[34];
    const float* snn_m = (const float*)d_in[35];
    const float* snn_v = (const float*)d_in[36];
    const float* plifw = (const float*)d_in[37];
    const float* attnw = (const float*)d_in[38];
    const float* attnb = (const float*)d_in[39];
    const float* c1_w  = (const float*)d_in[40];
    const float* c1_b  = (const float*)d_in[41];
    const float* c1_g  = (const float*)d_in[42];
    const float* c1_bb = (const float*)d_in[43];
    const float* c1_m  = (const float*)d_in[44];
    const float* c1_v  = (const float*)d_in[45];
    const float* c2_w  = (const float*)d_in[46];
    const float* c2_b  = (const float*)d_in[47];
    const float* c2_g  = (const float*)d_in[48];
    const float* c2_bb = (const float*)d_in[49];
    const float* c2_m  = (const float*)d_in[50];
    const float* c2_v  = (const float*)d_in[51];
    const float* c3_w  = (const float*)d_in[52];
    const float* c3_b  = (const float*)d_in[53];

    float* out = (float*)d_out;
    float* h1 = (float*)d_ws;                       // [64,192,2000]
    float* h2 = h1 + (size_t)Bn * Hh * Tt;          // [64,192,2000]

    dim3 grid((Tt + TILE_T - 1) / TILE_T, Bn);      // (16, 64)
    dim3 blk(256);

    // ---- TCN1: x[64,264,2000] -> h1, conv residual, d=1
    conv_tcn<3,1,264,0><<<grid, blk, 0, stream>>>(x, t1_w3, t1_b3, t1_g, t1_bb, t1_m, t1_v,
        t1_rw, t1_rb, nullptr, nullptr, nullptr, nullptr, h1, 0);
    conv_tcn<5,1,264,0><<<grid, blk, 0, stream>>>(x, t1_w5, t1_b5, t1_g, t1_bb, t1_m, t1_v,
        t1_rw, t1_rb, nullptr, nullptr, nullptr, nullptr, h1, 64);
    conv_tcn<7,1,264,0><<<grid, blk, 0, stream>>>(x, t1_w7, t1_b7, t1_g, t1_bb, t1_m, t1_v,
        t1_rw, t1_rb, nullptr, nullptr, nullptr, nullptr, h1, 128);

    // ---- TCN2: h1 -> h2, identity residual, d=2
    conv_tcn<3,2,192,1><<<grid, blk, 0, stream>>>(h1, t2_w3, t2_b3, t2_g, t2_bb, t2_m, t2_v,
        nullptr, nullptr, nullptr, nullptr, nullptr, nullptr, h2, 0);
    conv_tcn<5,2,192,1><<<grid, blk, 0, stream>>>(h1, t2_w5, t2_b5, t2_g, t2_bb, t2_m, t2_v,
        nullptr, nullptr, nullptr, nullptr, nullptr, nullptr, h2, 64);
    conv_tcn<7,2,192,1><<<grid, blk, 0, stream>>>(h1, t2_w7, t2_b7, t2_g, t2_bb, t2_m, t2_v,
        nullptr, nullptr, nullptr, nullptr, nullptr, nullptr, h2, 128);

    // ---- TCN3: h2 -> h1, identity residual + snn-BN fold, d=4
    conv_tcn<3,4,192,2><<<grid, blk, 0, stream>>>(h2, t3_w3, t3_b3, t3_g, t3_bb, t3_m, t3_v,
        nullptr, nullptr, snn_g, snn_bb, snn_m, snn_v, h1, 0);
    conv_tcn<5,4,192,2><<<grid, blk, 0, stream>>>(h2, t3_w5, t3_b5, t3_g, t3_bb, t3_m, t3_v,
        nullptr, nullptr, snn_g, snn_bb, snn_m, snn_v, h1, 64);
    conv_tcn<7,4,192,2><<<grid, blk, 0, stream>>>(h2, t3_w7, t3_b7, t3_g, t3_bb, t3_m, t3_v,
        nullptr, nullptr, snn_g, snn_bb, snn_m, snn_v, h1, 128);

    // ---- SNN scan + attention pooling + classifier
    snn_head<<<dim3(Bn), dim3(192), 0, stream>>>(h1, plifw, attnw, attnb,
        c1_w, c1_b, c1_g, c1_bb, c1_m, c1_v,
        c2_w, c2_b, c2_g, c2_bb, c2_m, c2_v, c3_w, c3_b, out);
}

// Round 2
// 1709.332 us; speedup vs baseline: 2.2881x; 2.2881x over previous
//
#include <hip/hip_runtime.h>
#include <cstdint>
#include <cstddef>

#define EPSV 1e-5f

typedef __attribute__((ext_vector_type(8))) short short8;
typedef __attribute__((ext_vector_type(4))) float f32x4;

constexpr int Bn = 64;
constexpr int Tt = 2000;
constexpr int Hh = 192;
constexpr int BN = 128;   // t-tile per block

__device__ __forceinline__ unsigned short f2bf(float f) {
    unsigned u = __float_as_uint(f);
    u += 0x7fff + ((u >> 16) & 1);          // RNE (no NaNs in this workload)
    return (unsigned short)(u >> 16);
}
__device__ __forceinline__ float bf2f(unsigned short h) {
    return __uint_as_float(((unsigned)h) << 16);
}

// Pre-transposed, zero-padded, hi/lo-split weights.  [slot][o=64][CIPAD], ci contiguous.
__device__ __align__(16) unsigned short g_w1h[15 * 64 * 288], g_w1l[15 * 64 * 288];
__device__ __align__(16) unsigned short g_w2h[15 * 64 * 192], g_w2l[15 * 64 * 192];
__device__ __align__(16) unsigned short g_w3h[15 * 64 * 192], g_w3l[15 * 64 * 192];
__device__ __align__(16) unsigned short g_rwh[192 * 288],     g_rwl[192 * 288];

// ---------------- weight prep: transpose [o][ci][K] -> [slot][o][ci], split hi/lo ----------------
__global__ void wprep(const float* __restrict__ w13, const float* __restrict__ w15, const float* __restrict__ w17,
                      const float* __restrict__ w23, const float* __restrict__ w25, const float* __restrict__ w27,
                      const float* __restrict__ w33, const float* __restrict__ w35, const float* __restrict__ w37,
                      const float* __restrict__ rw)
{
    const int region = blockIdx.y;
    const int i = blockIdx.x * 256 + threadIdx.x;
    if (region < 3) {
        const int CINs = (region == 0) ? 264 : 192;
        const int CP   = (region == 0) ? 288 : 192;
        const int tot  = 15 * 64 * CP;
        if (i >= tot) return;
        const int slot = i / (64 * CP);
        const int rem  = i - slot * (64 * CP);
        const int o    = rem / CP;
        const int ci   = rem - o * CP;
        int br, j;
        if (slot < 3)      { br = 0; j = slot; }
        else if (slot < 8) { br = 1; j = slot - 3; }
        else               { br = 2; j = slot - 8; }
        const int Kk = 3 + 2 * br;
        const float* w;
        if (region == 0)      w = (br == 0) ? w13 : ((br == 1) ? w15 : w17);
        else if (region == 1) w = (br == 0) ? w23 : ((br == 1) ? w25 : w27);
        else                  w = (br == 0) ? w33 : ((br == 1) ? w35 : w37);
        const float v = (ci < CINs) ? w[((size_t)o * CINs + ci) * Kk + j] : 0.f;
        const unsigned short hi = f2bf(v);
        const unsigned short lo = f2bf(v - bf2f(hi));
        unsigned short* ph = (region == 0) ? g_w1h : ((region == 1) ? g_w2h : g_w3h);
        unsigned short* pl = (region == 0) ? g_w1l : ((region == 1) ? g_w2l : g_w3l);
        ph[i] = hi; pl[i] = lo;
    } else {
        const int tot = 192 * 288;
        if (i >= tot) return;
        const int o = i / 288, ci = i - o * 288;
        const float v = (ci < 264) ? rw[o * 264 + ci] : 0.f;
        const unsigned short hi = f2bf(v);
        const unsigned short lo = f2bf(v - bf2f(hi));
        g_rwh[i] = hi; g_rwl[i] = lo;
    }
}

// ---------------- MFMA conv stage (bf16x3 split) ----------------
// Computes D[t][o] = sum_ci X^T[t,ci] W^T[ci,o] per tap, t-shift on the lane-mapped A rows.
// MODE: 0 = TCN1 (conv residual via rw), 1 = TCN2 (identity residual), 2 = TCN3 (+ snn-BN fold)
template<int STAGE, int MODE, int D, int CIN, int CIPAD, int HALO>
__global__ __launch_bounds__(384)
void conv_mfma(const float* __restrict__ xin,    // [B, CIN, T]
               const float* __restrict__ b3, const float* __restrict__ b5, const float* __restrict__ b7,
               const float* __restrict__ gg, const float* __restrict__ gb,
               const float* __restrict__ gm, const float* __restrict__ gv,
               const float* __restrict__ rb,     // MODE 0
               const float* __restrict__ sg, const float* __restrict__ sb,
               const float* __restrict__ sm, const float* __restrict__ sv,  // MODE 2
               float* __restrict__ hout)         // [B, 192, T]
{
    constexpr int TSPAN = BN + 2 * HALO;   // multiple of 8
    constexpr int NQ    = TSPAN / 4;
    constexpr int NCH   = CIPAD / 32;

    __shared__ unsigned short xt[TSPAN * 64];  // [t-row][32ci x {hi,lo} packed], 128B rows, XOR-swizzled

    const int tid    = threadIdx.x;
    const int w      = tid >> 6;
    const int l      = tid & 63;
    const int l15    = l & 15;
    const int l4     = l >> 4;
    const int branch = w >> 1;          // 0:k3 1:k5 2:k7
    const int thalf  = w & 1;
    const int K      = 3 + 2 * branch;
    const int PAD    = ((K - 1) / 2) * D;
    const int TB     = (branch == 0) ? 0 : ((branch == 1) ? 3 : 8);
    const int b      = blockIdx.y;
    const int t0     = blockIdx.x * BN;

    const unsigned short *wh, *wl;
    if constexpr (STAGE == 0)      { wh = g_w1h; wl = g_w1l; }
    else if constexpr (STAGE == 1) { wh = g_w2h; wl = g_w2l; }
    else                           { wh = g_w3h; wl = g_w3l; }

    f32x4 acc[4][4];
    f32x4 res[4][4];
#pragma unroll
    for (int a = 0; a < 4; ++a)
#pragma unroll
        for (int c = 0; c < 4; ++c)
#pragma unroll
            for (int i = 0; i < 4; ++i) { acc[a][c][i] = 0.f; if constexpr (MODE == 0) res[a][c][i] = 0.f; }

    for (int c = 0; c < NCH; ++c) {
        __syncthreads();
        // ---- stage + transpose + hi/lo split X chunk [32ci][TSPAN t] -> xt[t][...]
        for (int idx = tid; idx < 32 * NQ; idx += 384) {
            const int ciL = idx / NQ;
            const int q   = idx - ciL * NQ;
            const int ci  = c * 32 + ciL;
            const int tg  = t0 - HALO + 4 * q;
            float4 v = make_float4(0.f, 0.f, 0.f, 0.f);
            if (ci < CIN) {
                const float* rowp = xin + ((size_t)b * CIN + ci) * Tt;
                if (tg >= 0 && tg + 3 < Tt) {
                    v = *reinterpret_cast<const float4*>(rowp + tg);
                } else {
                    float* pv = &v.x;
#pragma unroll
                    for (int i = 0; i < 4; ++i) {
                        const int t = tg + i;
                        if (t >= 0 && t < Tt) pv[i] = rowp[t];
                    }
                }
            }
            const int colb = ((ciL >> 3) << 5) + ((ciL & 7) << 1);
            const float* pv = &v.x;
#pragma unroll
            for (int i = 0; i < 4; ++i) {
                const int r = 4 * q + i;
                const unsigned short hi = f2bf(pv[i]);
                const unsigned short lo = f2bf(pv[i] - bf2f(hi));
                const int a  = r * 128 + colb;
                const int sw = (r & 7) << 4;
                xt[(a ^ sw) >> 1]        = hi;
                xt[((a | 16) ^ sw) >> 1] = lo;
            }
        }
        __syncthreads();

        const int rbase = HALO + 64 * thalf + l15;
        for (int j = 0; j < K; ++j) {
            const int s = j * D - PAD;
            // ---- A frags (X^T rows; shift lands on per-lane row address)
            short8 Ah[4], Al[4];
#pragma unroll
            for (int tf = 0; tf < 4; ++tf) {
                const int r  = rbase + tf * 16 + s;
                const int a  = r * 128 + (l4 << 5);
                const int sw = (r & 7) << 4;
                Ah[tf] = *(const short8*)&xt[(a ^ sw) >> 1];
                Al[tf] = *(const short8*)&xt[((a | 16) ^ sw) >> 1];
            }
            // ---- B frags (weights, L2-hot)
            short8 Bh[4], Bl[4];
#pragma unroll
            for (int of = 0; of < 4; ++of) {
                const int widx = ((TB + j) * 64 + of * 16 + l15) * CIPAD + c * 32 + (l4 << 3);
                Bh[of] = *(const short8*)(wh + widx);
                Bl[of] = *(const short8*)(wl + widx);
            }
#pragma unroll
            for (int of = 0; of < 4; ++of)
#pragma unroll
                for (int tf = 0; tf < 4; ++tf) {
                    acc[tf][of] = __builtin_amdgcn_mfma_f32_16x16x32_bf16(Ah[tf], Bh[of], acc[tf][of], 0, 0, 0);
                    acc[tf][of] = __builtin_amdgcn_mfma_f32_16x16x32_bf16(Ah[tf], Bl[of], acc[tf][of], 0, 0, 0);
                    acc[tf][of] = __builtin_amdgcn_mfma_f32_16x16x32_bf16(Al[tf], Bh[of], acc[tf][of], 0, 0, 0);
                }
            if constexpr (MODE == 0) {
                if (j == (K - 1) / 2) {   // s == 0: reuse A frags for the 1x1 conv residual
#pragma unroll
                    for (int of = 0; of < 4; ++of) {
                        const int ridx = (branch * 64 + of * 16 + l15) * 288 + c * 32 + (l4 << 3);
                        const short8 Rh = *(const short8*)(g_rwh + ridx);
                        const short8 Rl = *(const short8*)(g_rwl + ridx);
#pragma unroll
                        for (int tf = 0; tf < 4; ++tf) {
                            res[tf][of] = __builtin_amdgcn_mfma_f32_16x16x32_bf16(Ah[tf], Rh, res[tf][of], 0, 0, 0);
                            res[tf][of] = __builtin_amdgcn_mfma_f32_16x16x32_bf16(Ah[tf], Rl, res[tf][of], 0, 0, 0);
                            res[tf][of] = __builtin_amdgcn_mfma_f32_16x16x32_bf16(Al[tf], Rh, res[tf][of], 0, 0, 0);
                        }
                    }
                }
            }
        }
    }

    // ---- epilogue: BN + ReLU + residual (+ snn-BN) + store
    const float* bias_b = (branch == 0) ? b3 : ((branch == 1) ? b5 : b7);
#pragma unroll
    for (int of = 0; of < 4; ++of) {
        const int og = branch * 64 + of * 16 + l15;
        const float sc = gg[og] * rsqrtf(gv[og] + EPSV);
        const float be = (bias_b[of * 16 + l15] - gm[og]) * sc + gb[og];
        float s2 = 0.f, b2 = 0.f, rbv = 0.f;
        if constexpr (MODE == 2) { s2 = sg[og] * rsqrtf(sv[og] + EPSV); b2 = sb[og] - sm[og] * s2; }
        if constexpr (MODE == 0) { rbv = rb[og]; }
#pragma unroll
        for (int tf = 0; tf < 4; ++tf) {
            const int t = t0 + 64 * thalf + tf * 16 + l4 * 4;
            if (t >= Tt) continue;
            float4 xr = make_float4(0.f, 0.f, 0.f, 0.f);
            if constexpr (MODE != 0)
                xr = *reinterpret_cast<const float4*>(xin + ((size_t)b * CIN + og) * Tt + t);
            const float* pxr = &xr.x;
            float o4[4];
#pragma unroll
            for (int i = 0; i < 4; ++i) {
                float v = acc[tf][of][i] * sc + be;
                v = fmaxf(v, 0.f);
                if constexpr (MODE == 0) v += res[tf][of][i] + rbv;
                else                     v += pxr[i];
                if constexpr (MODE == 2) v = v * s2 + b2;
                o4[i] = v;
            }
            *reinterpret_cast<float4*>(hout + ((size_t)b * Hh + og) * Tt + t) =
                make_float4(o4[0], o4[1], o4[2], o4[3]);
        }
    }
}

// ---------------- SNN + attention + classifier, one block per batch ----------------
__global__ __launch_bounds__(192) void snn_head(
    const float* __restrict__ hin,   // [B,192,T]  (snn-BN already folded)
    const float* __restrict__ plif,
    const float* __restrict__ aw, const float* __restrict__ ab,
    const float* __restrict__ c1w, const float* __restrict__ c1b,
    const float* __restrict__ c1g, const float* __restrict__ c1bb,
    const float* __restrict__ c1m, const float* __restrict__ c1v,
    const float* __restrict__ c2w, const float* __restrict__ c2b,
    const float* __restrict__ c2g, const float* __restrict__ c2bb,
    const float* __restrict__ c2m, const float* __restrict__ c2v,
    const float* __restrict__ c3w, const float* __restrict__ c3b,
    float* __restrict__ outp)        // [B,4]
{
    __shared__ uint32_t bits[192 * 65];
    __shared__ float scl[2048];
    __shared__ float red[8];
    __shared__ float pooled[192];
    __shared__ float z1[128];
    __shared__ float z2[64];

    const int tid = threadIdx.x;
    const int b   = blockIdx.x;
    const float decay = 1.f / (1.f + expf(-plif[0]));

    if (tid < 48) scl[2000 + tid] = 0.f;

    const float* row = hin + ((size_t)b * Hh + tid) * Tt;
    float v = 0.f;
    for (int c = 0; c < 62; ++c) {
        const float4* rq = reinterpret_cast<const float4*>(row + c * 32);
        float xa[32];
#pragma unroll
        for (int q = 0; q < 8; ++q) {
            float4 t4 = rq[q];
            xa[4 * q + 0] = t4.x; xa[4 * q + 1] = t4.y;
            xa[4 * q + 2] = t4.z; xa[4 * q + 3] = t4.w;
        }
        uint32_t wv = 0;
#pragma unroll
        for (int k = 0; k < 32; ++k) {
            v = fmaf(xa[k] - v, decay, v);
            if (v >= 1.f) { wv |= (1u << k); v = 0.f; }
        }
        bits[tid * 65 + c] = wv;
    }
    {
        const float4* rq = reinterpret_cast<const float4*>(row + 62 * 32);
        float xa[16];
#pragma unroll
        for (int q = 0; q < 4; ++q) {
            float4 t4 = rq[q];
            xa[4 * q + 0] = t4.x; xa[4 * q + 1] = t4.y;
            xa[4 * q + 2] = t4.z; xa[4 * q + 3] = t4.w;
        }
        uint32_t wv = 0;
#pragma unroll
        for (int k = 0; k < 16; ++k) {
            v = fmaf(xa[k] - v, decay, v);
            if (v >= 1.f) { wv |= (1u << k); v = 0.f; }
        }
        bits[tid * 65 + 62] = wv;
    }
    __syncthreads();

    const float tanh1 = 0.7615941559557649f;
    const float abv   = ab[0];
    for (int t = tid; t < Tt; t += 192) {
        const int wd = t >> 5, bp = t & 31;
        float s = 0.f;
#pragma unroll 8
        for (int hh = 0; hh < 192; ++hh)
            s += ((bits[hh * 65 + wd] >> bp) & 1u) ? aw[hh] : 0.f;
        scl[t] = s * tanh1 + abv;
    }
    __syncthreads();

    float lm = -1e30f;
    for (int t = tid; t < Tt; t += 192) lm = fmaxf(lm, scl[t]);
#pragma unroll
    for (int off = 32; off > 0; off >>= 1) lm = fmaxf(lm, __shfl_xor(lm, off));
    if ((tid & 63) == 0) red[tid >> 6] = lm;
    __syncthreads();
    const float m = fmaxf(red[0], fmaxf(red[1], red[2]));
    float ls = 0.f;
    for (int t = tid; t < Tt; t += 192) {
        float e = expf(scl[t] - m);
        scl[t] = e;
        ls += e;
    }
#pragma unroll
    for (int off = 32; off > 0; off >>= 1) ls += __shfl_xor(ls, off);
    if ((tid & 63) == 0) red[4 + (tid >> 6)] = ls;
    __syncthreads();
    const float inv = 1.f / (red[4] + red[5] + red[6]);

    float p = 0.f;
    for (int wd = 0; wd < 63; ++wd) {
        uint32_t bw = bits[tid * 65 + wd];
        if (bw) {
#pragma unroll
            for (int k = 0; k < 32; ++k)
                if ((bw >> k) & 1u) p += scl[wd * 32 + k];
        }
    }
    pooled[tid] = p * inv;
    __syncthreads();

    if (tid < 128) {
        const float4* wr = reinterpret_cast<const float4*>(c1w + (size_t)tid * 192);
        const float4* pr = reinterpret_cast<const float4*>(pooled);
        float s = 0.f;
#pragma unroll 8
        for (int q = 0; q < 48; ++q) {
            float4 wv4 = wr[q]; float4 pv4 = pr[q];
            s += wv4.x * pv4.x + wv4.y * pv4.y + wv4.z * pv4.z + wv4.w * pv4.w;
        }
        s += c1b[tid];
        s = (s - c1m[tid]) * (c1g[tid] / sqrtf(c1v[tid] + EPSV)) + c1bb[tid];
        s = s * 0.5f * (1.f + erff(s * 0.70710678118654752f));
        z1[tid] = s;
    }
    __syncthreads();
    if (tid < 64) {
        const float4* wr = reinterpret_cast<const float4*>(c2w + (size_t)tid * 128);
        const float4* zr = reinterpret_cast<const float4*>(z1);
        float s = 0.f;
#pragma unroll 8
        for (int q = 0; q < 32; ++q) {
            float4 wv4 = wr[q]; float4 zv4 = zr[q];
            s += wv4.x * zv4.x + wv4.y * zv4.y + wv4.z * zv4.z + wv4.w * zv4.w;
        }
        s += c2b[tid];
        s = (s - c2m[tid]) * (c2g[tid] / sqrtf(c2v[tid] + EPSV)) + c2bb[tid];
        s = s * 0.5f * (1.f + erff(s * 0.70710678118654752f));
        z2[tid] = s;
    }
    __syncthreads();
    if (tid < 4) {
        float s = c3b[tid];
#pragma unroll 8
        for (int hh = 0; hh < 64; ++hh) s += z2[hh] * c3w[tid * 64 + hh];
        outp[b * 4 + tid] = s;
    }
}

extern "C" void kernel_launch(void* const* d_in, const int* in_sizes, int n_in,
                              void* d_out, int out_size, void* d_ws, size_t ws_size,
                              hipStream_t stream) {
    (void)in_sizes; (void)n_in; (void)out_size; (void)ws_size;
    const float* x     = (const float*)d_in[0];
    const float* t1_w3 = (const float*)d_in[1];
    const float* t1_b3 = (const float*)d_in[2];
    const float* t1_w5 = (const float*)d_in[3];
    const float* t1_b5 = (const float*)d_in[4];
    const float* t1_w7 = (const float*)d_in[5];
    const float* t1_b7 = (const float*)d_in[6];
    const float* t1_g  = (const float*)d_in[7];
    const float* t1_bb = (const float*)d_in[8];
    const float* t1_m  = (const float*)d_in[9];
    const float* t1_v  = (const float*)d_in[10];
    const float* t2_w3 = (const float*)d_in[11];
    const float* t2_b3 = (const float*)d_in[12];
    const float* t2_w5 = (const float*)d_in[13];
    const float* t2_b5 = (const float*)d_in[14];
    const float* t2_w7 = (const float*)d_in[15];
    const float* t2_b7 = (const float*)d_in[16];
    const float* t2_g  = (const float*)d_in[17];
    const float* t2_bb = (const float*)d_in[18];
    const float* t2_m  = (const float*)d_in[19];
    const float* t2_v  = (const float*)d_in[20];
    const float* t3_w3 = (const float*)d_in[21];
    const float* t3_b3 = (const float*)d_in[22];
    const float* t3_w5 = (const float*)d_in[23];
    const float* t3_b5 = (const float*)d_in[24];
    const float* t3_w7 = (const float*)d_in[25];
    const float* t3_b7 = (const float*)d_in[26];
    const float* t3_g  = (const float*)d_in[27];
    const float* t3_bb = (const float*)d_in[28];
    const float* t3_m  = (const float*)d_in[29];
    const float* t3_v  = (const float*)d_in[30];
    const float* t1_rw = (const float*)d_in[31];
    const float* t1_rb = (const float*)d_in[32];
    const float* snn_g = (const float*)d_in[33];
    const float* snn_bb= (const float*)d_in[34];
    const float* snn_m = (const float*)d_in[35];
    const float* snn_v = (const float*)d_in[36];
    const float* plifw = (const float*)d_in[37];
    const float* attnw = (const float*)d_in[38];
    const float* attnb = (const float*)d_in[39];
    const float* c1_w  = (const float*)d_in[40];
    const float* c1_b  = (const float*)d_in[41];
    const float* c1_g  = (const float*)d_in[42];
    const float* c1_bb = (const float*)d_in[43];
    const float* c1_m  = (const float*)d_in[44];
    const float* c1_v  = (const float*)d_in[45];
    const float* c2_w  = (const float*)d_in[46];
    const float* c2_b  = (const float*)d_in[47];
    const float* c2_g  = (const float*)d_in[48];
    const float* c2_bb = (const float*)d_in[49];
    const float* c2_m  = (const float*)d_in[50];
    const float* c2_v  = (const float*)d_in[51];
    const float* c3_w  = (const float*)d_in[52];
    const float* c3_b  = (const float*)d_in[53];

    float* out = (float*)d_out;
    float* h1 = (float*)d_ws;                       // [64,192,2000]
    float* h2 = h1 + (size_t)Bn * Hh * Tt;          // [64,192,2000]

    // ---- weight prep (writes module __device__ arrays; tiny)
    wprep<<<dim3(1080, 4), dim3(256), 0, stream>>>(
        t1_w3, t1_w5, t1_w7, t2_w3, t2_w5, t2_w7, t3_w3, t3_w5, t3_w7, t1_rw);

    dim3 grid((Tt + BN - 1) / BN, Bn);   // (16, 64)
    dim3 blk(384);

    // ---- TCN1: x -> h1 (d=1, conv residual)
    conv_mfma<0, 0, 1, 264, 288, 4><<<grid, blk, 0, stream>>>(
        x, t1_b3, t1_b5, t1_b7, t1_g, t1_bb, t1_m, t1_v,
        t1_rb, nullptr, nullptr, nullptr, nullptr, h1);

    // ---- TCN2: h1 -> h2 (d=2, identity residual)
    conv_mfma<1, 1, 2, 192, 192, 8><<<grid, blk, 0, stream>>>(
        h1, t2_b3, t2_b5, t2_b7, t2_g, t2_bb, t2_m, t2_v,
        nullptr, nullptr, nullptr, nullptr, nullptr, h2);

    // ---- TCN3: h2 -> h1 (d=4, identity residual + snn-BN fold)
    conv_mfma<2, 2, 4, 192, 192, 12><<<grid, blk, 0, stream>>>(
        h2, t3_b3, t3_b5, t3_b7, t3_g, t3_bb, t3_m, t3_v,
        nullptr, snn_g, snn_bb, snn_m, snn_v, h1);

    // ---- SNN scan + attention pooling + classifier
    snn_head<<<dim3(Bn), dim3(192), 0, stream>>>(h1, plifw, attnw, attnb,
        c1_w, c1_b, c1_g, c1_bb, c1_m, c1_v,
        c2_w, c2_b, c2_g, c2_bb, c2_m, c2_v, c3_w, c3_b, out);
}